// Round 14
// baseline (1661.487 us; speedup 1.0000x reference)
//
#include <hip/hip_runtime.h>
#include <hip/hip_bf16.h>
#include <cstdint>

// GRU scan: T=256, B=64, H=1024.
// gi = x@Wi + bi precomputed with one bf16 MFMA GEMM; then a persistent
// 256-WG x 256-thread kernel walks 256 sequential steps.
// Structure (round 13): 8 groups x 8 batches; 32 WGs/group x 32 j-cols;
// single-writer 64B row-segments; full canary coverage; sentinel-in-data
// (hseq[257][64][1024] bf16, 0xFF sentinel = -NaN, unproducible).
// NEW this round:
//  - SPECULATIVE bulk: chunk for slot t+1 is issued right after publishing
//    slot t+1 (double-buffered wA/wB). After the cheap canary clears, the
//    already-arrived data is checked; reload only if stale. Saves the
//    serial bulk-fetch RTT whenever the first canary probe succeeds.
//  - SELF-SLICE FROM LDS: the one k-slice produced by this WG itself (which
//    can never be speculatively valid) is read from hsh (parity-buffered,
//    one extra barrier/step) instead of via MALL; its canary lane is
//    redirected to a remote producer; its words are excluded from checks.

#define TT 256
#define BB 64
#define HH 1024
#define H3 3072

typedef __attribute__((ext_vector_type(8))) short s16x8;
typedef __attribute__((ext_vector_type(4))) float f32x4;
typedef __attribute__((ext_vector_type(4))) unsigned int u32x4;
typedef unsigned long long ull;

__device__ __forceinline__ float fast_sigmoid(float x) {
  float e = __expf(-fabsf(x));
  float s = 1.0f / (1.0f + e);
  return x >= 0.0f ? s : 1.0f - s;
}
__device__ __forceinline__ float fast_tanh(float x) {
  float e = __expf(-2.0f * fabsf(x));
  float t = (1.0f - e) / (1.0f + e);
  return x >= 0.0f ? t : -t;
}
__device__ __forceinline__ f32x4 mfma16(s16x8 a, s16x8 b, f32x4 c) {
  return __builtin_amdgcn_mfma_f32_16x16x32_bf16(a, b, c, 0, 0, 0);
}

#define LD8(p) __hip_atomic_load((p), __ATOMIC_RELAXED, __HIP_MEMORY_SCOPE_AGENT)
#define ST8(p, v) __hip_atomic_store((p), (v), __ATOMIC_RELAXED, __HIP_MEMORY_SCOPE_AGENT)

// opaque 16B load: compiler cannot rematerialize/sink it into the loop
__device__ __forceinline__ u32x4 ld16_opaque(const char* p) {
  u32x4 r;
  asm volatile("global_load_dwordx4 %0, %1, off\n\t"
               "s_waitcnt vmcnt(0)"
               : "=&v"(r) : "v"(p) : "memory");
  return r;
}

// ---------------- setup kernels ----------------

__global__ void k_cvt_x(const float* __restrict__ x, __hip_bfloat16* __restrict__ xb, int n) {
  int i = (blockIdx.x * blockDim.x + threadIdx.x) * 4;
  if (i + 3 < n) {
    float4 v = *reinterpret_cast<const float4*>(x + i);
    xb[i + 0] = __float2bfloat16(v.x);
    xb[i + 1] = __float2bfloat16(v.y);
    xb[i + 2] = __float2bfloat16(v.z);
    xb[i + 3] = __float2bfloat16(v.w);
  }
}

// W [1024][3072] f32 -> WT [3072][1024] bf16
__global__ void k_transpose_w(const float* __restrict__ W, __hip_bfloat16* __restrict__ WT) {
  __shared__ float tile[32][33];
  int c0 = blockIdx.x * 32, r0 = blockIdx.y * 32;
  int tx = threadIdx.x & 31, ty = threadIdx.x >> 5;  // 256 threads: 32x8
#pragma unroll
  for (int i = 0; i < 32; i += 8)
    tile[ty + i][tx] = W[(size_t)(r0 + ty + i) * H3 + c0 + tx];
  __syncthreads();
#pragma unroll
  for (int i = 0; i < 32; i += 8)
    WT[(size_t)(c0 + ty + i) * HH + r0 + tx] = __float2bfloat16(tile[tx][ty + i]);
}

// ---------------- gi = x @ Wi + bi  (bf16 MFMA, 128x128 tile, BK=32) ----------------

template <bool GIF32>
__global__ __launch_bounds__(256, 2) void k_gemm_gi(
    const __hip_bfloat16* __restrict__ A,   // [16384][1024] x bf16
    const __hip_bfloat16* __restrict__ Bt,  // [3072][1024]  Wi^T bf16
    const float* __restrict__ bi,           // [3072]
    void* __restrict__ gi)                  // [16384][3072] f32 or bf16
{
  __shared__ __align__(16) __hip_bfloat16 As[128 * 32];
  __shared__ __align__(16) __hip_bfloat16 Bs[128 * 32];
  const int bid = blockIdx.x;
  const int mt = bid / 24, nt = bid % 24;
  const int m0 = mt * 128, n0 = nt * 128;
  const int tid = threadIdx.x, lane = tid & 63, w = tid >> 6;
  const int wm = w & 1, wn = w >> 1;

  f32x4 acc[4][4];
#pragma unroll
  for (int ai = 0; ai < 4; ++ai)
#pragma unroll
    for (int bj = 0; bj < 4; ++bj) acc[ai][bj] = (f32x4){0.f, 0.f, 0.f, 0.f};

  for (int k0 = 0; k0 < HH; k0 += 32) {
#pragma unroll
    for (int i = 0; i < 2; ++i) {
      const int c = w + i * 4;
      const int idx = c * 64 + lane;
      const int row = idx >> 2, slot = idx & 3;
      __builtin_amdgcn_global_load_lds(
          (const __attribute__((address_space(1))) void*)(A + (size_t)(m0 + row) * HH + k0 + slot * 8),
          (__attribute__((address_space(3))) void*)(As + c * 512), 16, 0, 0);
      __builtin_amdgcn_global_load_lds(
          (const __attribute__((address_space(1))) void*)(Bt + (size_t)(n0 + row) * HH + k0 + slot * 8),
          (__attribute__((address_space(3))) void*)(Bs + c * 512), 16, 0, 0);
    }
    __syncthreads();
    s16x8 af[4], bf[4];
#pragma unroll
    for (int ai = 0; ai < 4; ++ai) {
      int r = wm * 64 + ai * 16 + (lane & 15);
      af[ai] = *reinterpret_cast<const s16x8*>(As + r * 32 + (lane >> 4) * 8);
    }
#pragma unroll
    for (int bj = 0; bj < 4; ++bj) {
      int r = wn * 64 + bj * 16 + (lane & 15);
      bf[bj] = *reinterpret_cast<const s16x8*>(Bs + r * 32 + (lane >> 4) * 8);
    }
#pragma unroll
    for (int ai = 0; ai < 4; ++ai)
#pragma unroll
      for (int bj = 0; bj < 4; ++bj) acc[ai][bj] = mfma16(af[ai], bf[bj], acc[ai][bj]);
    __syncthreads();
  }

#pragma unroll
  for (int ai = 0; ai < 4; ++ai) {
#pragma unroll
    for (int reg = 0; reg < 4; ++reg) {
      const size_t row = (size_t)m0 + wm * 64 + ai * 16 + (lane >> 4) * 4 + reg;
#pragma unroll
      for (int bj = 0; bj < 4; ++bj) {
        const int col = n0 + wn * 64 + bj * 16 + (lane & 15);
        float v = acc[ai][bj][reg] + bi[col];
        if (GIF32)
          reinterpret_cast<float*>(gi)[row * H3 + col] = v;
        else
          reinterpret_cast<__hip_bfloat16*>(gi)[row * H3 + col] = __float2bfloat16(v);
      }
    }
  }
}

// ---------------- persistent step kernel ----------------

// issue 16 x 8B loads of chunk at CH into W (no explicit wait)
#define ISSUE16(W, CH)                                   \
  do {                                                   \
    _Pragma("unroll") for (int i_ = 0; i_ < 8; ++i_) {   \
      W[2 * i_ + 0] = LD8((CH) + i_ * 8 + 0);            \
      W[2 * i_ + 1] = LD8((CH) + i_ * 8 + 1);            \
    }                                                    \
  } while (0)

// one scan step: consume CUR (slot T, speculatively loaded), publish slot
// T+1, speculatively issue NXT (slot T+1).
#define STEP(T, CUR, NXT)                                                      \
  do {                                                                         \
    const int t_ = (T);                                                        \
    const int p_ = t_ & 1;        /* write parity (partials, hsh) */           \
    const int ph_ = (t_ + 1) & 1; /* read parity of hsh (h_{t-1}) */           \
    const int rstA_ = resets[t_ * BB + bg0 + alr];                             \
    const __hip_bfloat16* rd_ = hseq + (size_t)t_ * 65536;                     \
    { /* cheap canary spin: full (producer,row) coverage, self redirected */   \
      const ull* cp_ = reinterpret_cast<const ull*>(rd_ + cansub);             \
      int gq_ = 0;                                                             \
      ull c_;                                                                  \
      do {                                                                     \
        c_ = LD8(cp_);                                                         \
      } while (__any((int)(c_ == ~0ull)) && ++gq_ < (1 << 20));                \
    }                                                                          \
    { /* speculative-data check (self words excluded); reload iff stale */     \
      unsigned bad_ = 0;                                                       \
      _Pragma("unroll") for (int i_ = 0; i_ < 16; ++i_)                        \
        if ((i_ >> 1) != kselfw) bad_ |= (unsigned)(CUR[i_] == ~0ull);         \
      if (__any((int)bad_)) {                                                  \
        const ull* ch_ = reinterpret_cast<const ull*>(rd_ + chsub);            \
        int gq_ = 0;                                                           \
        for (;;) {                                                             \
          ISSUE16(CUR, ch_);                                                   \
          unsigned b2_ = 0;                                                    \
          _Pragma("unroll") for (int i_ = 0; i_ < 16; ++i_)                    \
            if ((i_ >> 1) != kselfw) b2_ |= (unsigned)(CUR[i_] == ~0ull);      \
          if (!__any((int)b2_) || ++gq_ >= (1 << 18)) break;                   \
        }                                                                      \
      }                                                                        \
    }                                                                          \
    /* 48 MFMA: gates r,z from LDS, gate n from regs; self k-slice from hsh */ \
    const ull amask_ = ((l15 < 8) && !rstA_) ? ~0ull : 0ull;                   \
    f32x4 acc_[6];                                                             \
    _Pragma("unroll") for (int tl_ = 0; tl_ < 6; ++tl_)                        \
      acc_[tl_] = (f32x4){0.f, 0.f, 0.f, 0.f};                                 \
    _Pragma("unroll") for (int kk_ = 0; kk_ < 8; ++kk_) {                      \
      union { ull q[2]; s16x8 v; } u_;                                         \
      if (kk_ == kselfw) {                                                     \
        u_.v = *reinterpret_cast<const s16x8*>(&hsh[ph_][alr][koff]);          \
        u_.q[0] &= amask_;                                                     \
        u_.q[1] &= amask_;                                                     \
      } else {                                                                 \
        u_.q[0] = CUR[2 * kk_ + 0] & amask_;                                   \
        u_.q[1] = CUR[2 * kk_ + 1] & amask_;                                   \
      }                                                                        \
      const int kb_ = wave * 512 + kk_ * 64 + (lane >> 4) * 16;                \
      _Pragma("unroll") for (int nt_ = 0; nt_ < 2; ++nt_) {                    \
        const int rR_ = nt_ * 16 + l15;                                        \
        const int rZ_ = 32 + nt_ * 16 + l15;                                   \
        s16x8 br_ = *reinterpret_cast<const s16x8*>(                           \
            Wlds + rR_ * 2048 + (kb_ ^ ((rR_ & 7) << 4)));                     \
        s16x8 bz_ = *reinterpret_cast<const s16x8*>(                           \
            Wlds + rZ_ * 2048 + (kb_ ^ ((rZ_ & 7) << 4)));                     \
        acc_[0 + nt_] = mfma16(u_.v, br_, acc_[0 + nt_]);                      \
        acc_[2 + nt_] = mfma16(u_.v, bz_, acc_[2 + nt_]);                      \
        acc_[4 + nt_] =                                                        \
            mfma16(u_.v, __builtin_bit_cast(s16x8, bnf[nt_ * 8 + kk_]),        \
                   acc_[4 + nt_]);                                             \
      }                                                                        \
    }                                                                          \
    if (lane < 32) {                                                           \
      _Pragma("unroll") for (int tl_ = 0; tl_ < 6; ++tl_)                      \
        part[p_][wave][tl_][lane] = acc_[tl_];                                 \
    }                                                                          \
    __syncthreads();                                                           \
    /* distributed epilogue: each thread its (b,j) cell */                     \
    const int nt_ = jl >> 4;                                                   \
    const int li_ = ((bl >> 2) << 4) | (jl & 15), el_ = bl & 3;                \
    float sR_ = part[p_][0][0 + nt_][li_][el_];                                \
    float sZ_ = part[p_][0][2 + nt_][li_][el_];                                \
    float sN_ = part[p_][0][4 + nt_][li_][el_];                                \
    _Pragma("unroll") for (int ww_ = 1; ww_ < 4; ++ww_) {                      \
      sR_ += part[p_][ww_][0 + nt_][li_][el_];                                 \
      sZ_ += part[p_][ww_][2 + nt_][li_][el_];                                 \
      sN_ += part[p_][ww_][4 + nt_][li_][el_];                                 \
    }                                                                          \
    const float hprev_ = rstE ? 0.f : hp;                                      \
    const float rg_ = fast_sigmoid(giR + sR_);                                 \
    const float zg_ = fast_sigmoid(giZ + sZ_);                                 \
    const float ng_ = fast_tanh(giN + rg_ * (sN_ + bnj));                      \
    const float hnew_ = (1.0f - zg_) * ng_ + zg_ * hprev_;                     \
    hp = hnew_;                                                                \
    hsh[p_][bl][jl] = __float2bfloat16(hnew_);                                 \
    /* publish h_t to slot t+1: lanes 0-15 of each wave, 8B agent stores */    \
    if (lane < 16) {                                                           \
      const int prow_ = wave * 2 + (lane >> 3);                                \
      const int pw_ = lane & 7;                                                \
      ull pv_ = *reinterpret_cast<const ull*>(&hsh[p_][prow_][pw_ * 4]);       \
      ST8(reinterpret_cast<ull*>(hseq + (size_t)(t_ + 1) * 65536 +             \
                                 (size_t)(bg0 + prow_) * HH + j0 + pw_ * 4),   \
          pv_);                                                                \
    }                                                                          \
    /* speculative issue of next slot's chunk (flies during tail + spin) */    \
    {                                                                          \
      const ull* chn_ = reinterpret_cast<const ull*>(                          \
          hseq + (size_t)(t_ + 1) * 65536 + chsub);                            \
      ISSUE16(NXT, chn_);                                                      \
    }                                                                          \
    /* ys write (off the inter-WG critical path) */                            \
    __builtin_nontemporal_store(                                               \
        hnew_, out + 65536 + (size_t)t_ * 65536 + (size_t)b * HH + j);         \
    /* prefetch next step's gi / reset */                                      \
    const int tn_ = (t_ + 1 < TT) ? t_ + 1 : t_;                               \
    rstE = resets[tn_ * BB + b];                                               \
    if (GIF32) {                                                               \
      const float* grow_ =                                                     \
          reinterpret_cast<const float*>(gi_) + (size_t)(tn_ * BB + b) * H3;   \
      giR = grow_[j]; giZ = grow_[HH + j]; giN = grow_[2 * HH + j];            \
    } else {                                                                   \
      const __hip_bfloat16* grow_ =                                            \
          reinterpret_cast<const __hip_bfloat16*>(gi_) +                       \
          (size_t)(tn_ * BB + b) * H3;                                         \
      giR = __bfloat162float(grow_[j]);                                        \
      giZ = __bfloat162float(grow_[HH + j]);                                   \
      giN = __bfloat162float(grow_[2 * HH + j]);                               \
    }                                                                          \
    __syncthreads(); /* hsh[p_] complete before next step's self-read */       \
  } while (0)

// 256 WGs x 256 threads (4 waves). 8 groups (8 batches) x 32 WGs (32 j-cols).
// Wave w owns K-chunk [256w,256w+256) = producers [8w,8w+8).
// Epilogue: thread tid owns cell (b = bg0 + tid>>5, j = j0 + (tid&31)).
template <bool GIF32>
__global__ __launch_bounds__(256, 1) void k_gru(
    const void* __restrict__ gi_,
    const int* __restrict__ resets,   // [256][64]
    const float* __restrict__ h0,     // [64][1024]
    const float* __restrict__ bn,     // [1024]
    const __hip_bfloat16* __restrict__ WhT,  // [3072][1024]
    __hip_bfloat16* hseq,                    // [257][64][1024] sentinel-filled
    float* __restrict__ out)                 // [64*1024 hfinal | 256*64*1024 ys]
{
  __shared__ __align__(16) char Wlds[64 * 2048];         // gates r,z (128 KiB)
  __shared__ __align__(16) f32x4 part[2][4][6][32];      // 24 KiB partials
  __shared__ __align__(16) __hip_bfloat16 hsh[2][8][32]; // 1 KiB transpose, parity

  const int tid = threadIdx.x;
  const int wave = tid >> 6, lane = tid & 63;
  const int wg = blockIdx.x;
  const int g = wg & 7, s = wg >> 3;   // group, col-slot
  const int bg0 = g * 8, j0 = s * 32;
  const int l15 = lane & 15;

  // ---- per-thread epilogue cell: (b, j) ----
  const int bl = tid >> 5;   // 0..7 local batch (wave w covers rows 2w, 2w+1)
  const int jl = tid & 31;   // 0..31 local col
  const int b = bg0 + bl, j = j0 + jl;
  const float bnj = bn[j];
  float hp = h0[(size_t)b * HH + j];

  // publish slot 0 (= h_{-1}) EARLY: wave-local transpose -> 8B agent stores
  hsh[1][bl][jl] = __float2bfloat16(hp);  // step 0 reads parity 1
  if (lane < 16) {
    const int prow = wave * 2 + (lane >> 3);
    const int pw = lane & 7;
    ull pv = *reinterpret_cast<const ull*>(&hsh[1][prow][pw * 4]);
    ST8(reinterpret_cast<ull*>(hseq + (size_t)(bg0 + prow) * HH + j0 + pw * 4), pv);
  }

  // ---- stage Wh gates r,z into LDS (XOR-swizzled rows of 2048B) ----
  for (int u = tid; u < 64 * 128; u += 256) {
    const int row = u >> 7, sl = u & 127;
    const int gate = row >> 5, jj = row & 31;
    u32x4 v = *reinterpret_cast<const u32x4*>(WhT + (size_t)(gate * HH + j0 + jj) * HH + sl * 8);
    const int byte = row * 2048 + ((sl * 16) ^ ((row & 7) << 4));
    *reinterpret_cast<u32x4*>(Wlds + byte) = v;
  }

  // ---- gate n fragments in registers (opaque loads, remat-proof) ----
  u32x4 bnf[16];
#pragma unroll
  for (int nt = 0; nt < 2; ++nt)
#pragma unroll
    for (int kk = 0; kk < 8; ++kk)
      bnf[nt * 8 + kk] = ld16_opaque(reinterpret_cast<const char*>(
          WhT + (size_t)(2 * HH + j0 + nt * 16 + l15) * HH + wave * 256 + kk * 32 + (lane >> 4) * 8));

  // step-0 gi / reset prefetch
  int rstE = resets[b];
  float giR, giZ, giN;
  if (GIF32) {
    const float* grow = reinterpret_cast<const float*>(gi_) + (size_t)b * H3;
    giR = grow[j]; giZ = grow[HH + j]; giN = grow[2 * HH + j];
  } else {
    const __hip_bfloat16* grow = reinterpret_cast<const __hip_bfloat16*>(gi_) + (size_t)b * H3;
    giR = __bfloat162float(grow[j]);
    giZ = __bfloat162float(grow[HH + j]);
    giN = __bfloat162float(grow[2 * HH + j]);
  }

  // ---- consumer geometry ----
  const int alr = lane & 7;           // A row (real); l15>=8 lanes duplicate
  const int koff = (lane >> 4) * 8;   // k sub-offset (elements) in a 32-elem step
  // self k-slice: the producer that is THIS WG (k-cols j0..j0+32 of wave s>>3)
  const int kselfw = (wave == (s >> 3)) ? (s & 7) : -1;
  // canary: lane = cprod*8 + crow; self-producer redirected to a remote one
  const int cprod0 = lane >> 3, crow = lane & 7;
  const int cprod = (cprod0 == kselfw) ? (cprod0 ^ 1) : cprod0;
  const size_t cansub = (size_t)(bg0 + crow) * HH + (wave * 8 + cprod) * 32 + 28;
  const size_t chsub = (size_t)(bg0 + alr) * HH + wave * 256 + koff;

  __syncthreads();  // Wlds + hsh[1] staged

  // prologue: speculative issue of slot-0 chunk
  ull wA[16], wB[16];
  {
    const ull* ch0 = reinterpret_cast<const ull*>(hseq + chsub);
    ISSUE16(wA, ch0);
  }

  for (int t = 0; t < TT; t += 2) {
    STEP(t, wA, wB);
    STEP(t + 1, wB, wA);
  }

  out[(size_t)b * HH + j] = hp;
}

// ---------------- launch ----------------

extern "C" void kernel_launch(void* const* d_in, const int* in_sizes, int n_in,
                              void* d_out, int out_size, void* d_ws, size_t ws_size,
                              hipStream_t stream) {
  const float* x      = (const float*)d_in[0];  // [256,64,1024]
  const int* resets   = (const int*)d_in[1];    // [256,64]
  const float* h0     = (const float*)d_in[2];  // [64,1024]
  const float* Wi     = (const float*)d_in[3];  // [1024,3072]
  const float* bi     = (const float*)d_in[4];  // [3072]
  const float* Wh     = (const float*)d_in[5];  // [1024,3072]
  const float* bn     = (const float*)d_in[6];  // [1024]
  (void)in_sizes; (void)n_in; (void)out_size;

  char* ws = (char*)d_ws;
  // region0: xb [16384][1024] bf16 (33,554,432 B), dead after gemm, then
  //          reused as hseq [257][64][1024] bf16 (33,685,504 B)
  __hip_bfloat16* xb   = (__hip_bfloat16*)(ws);
  __hip_bfloat16* hseq = (__hip_bfloat16*)(ws);
  __hip_bfloat16* WiT  = (__hip_bfloat16*)(ws + 33685504);  // 6,291,456 B
  __hip_bfloat16* WhT  = (__hip_bfloat16*)(ws + 39976960);  // 6,291,456 B
  void* gi             = (void*)(ws + 46268416);

  const bool gif32 = ws_size >= 46268416ull + (size_t)16384 * 3072 * 4;

  k_cvt_x<<<16384, 256, 0, stream>>>(x, xb, TT * BB * HH);
  k_transpose_w<<<dim3(96, 32), 256, 0, stream>>>(Wi, WiT);
  k_transpose_w<<<dim3(96, 32), 256, 0, stream>>>(Wh, WhT);
  if (gif32) {
    k_gemm_gi<true><<<3072, 256, 0, stream>>>(xb, WiT, bi, gi);
    // xb dead; sentinel-fill hseq (0xFF = -NaN bf16 words)
    hipMemsetAsync(hseq, 0xFF, 33685504, stream);
    k_gru<true><<<256, 256, 0, stream>>>(gi, resets, h0, bn, WhT, hseq, (float*)d_out);
  } else {
    k_gemm_gi<false><<<3072, 256, 0, stream>>>(xb, WiT, bi, gi);
    hipMemsetAsync(hseq, 0xFF, 33685504, stream);
    k_gru<false><<<256, 256, 0, stream>>>(gi, resets, h0, bn, WhT, hseq, (float*)d_out);
  }
}

// Round 15
// 1283.192 us; speedup vs baseline: 1.2948x; 1.2948x over previous
//
#include <hip/hip_runtime.h>
#include <hip/hip_bf16.h>
#include <cstdint>

// GRU scan: T=256, B=64, H=1024.  FINAL (round-10 structure, best measured).
// gi = x@Wi + bi precomputed with one bf16 MFMA GEMM; then a persistent
// 256-WG x 256-thread kernel walks 256 sequential steps.
// Protocol: sentinel-in-data:
//  - canary covers ALL 16 producers of each wave's K-chunk (16 prod x 4 rows)
//  - ONE bulk chunk load after canary; verify loop (retries rare)
//  - distributed epilogue (each thread owns one (b,j) cell); per-wave publish
// h_t goes to a fresh slot of hseq[257][64][1024] bf16 (sentinel 0xFF words,
// -NaN bf16, unproducible by finite GRU arithmetic). No flags, no ACK drain.
// Measured: total 1282 us (k_gru 1155, 4.5 us/step) — synchronization-
// latency-bound: MfmaUtil 3.6%, VALUBusy 6.8%, HBM 4%. Step floor =
// publish->MALL-visible + detect + fetch RTT chain; R11/R14 (speculative
// fetch) and R6-R8 (XCD-local L2) attempts to break it all regressed.

#define TT 256
#define BB 64
#define HH 1024
#define H3 3072

typedef __attribute__((ext_vector_type(8))) short s16x8;
typedef __attribute__((ext_vector_type(4))) float f32x4;
typedef __attribute__((ext_vector_type(4))) unsigned int u32x4;
typedef unsigned long long ull;

__device__ __forceinline__ float fast_sigmoid(float x) {
  float e = __expf(-fabsf(x));
  float s = 1.0f / (1.0f + e);
  return x >= 0.0f ? s : 1.0f - s;
}
__device__ __forceinline__ float fast_tanh(float x) {
  float e = __expf(-2.0f * fabsf(x));
  float t = (1.0f - e) / (1.0f + e);
  return x >= 0.0f ? t : -t;
}
__device__ __forceinline__ f32x4 mfma16(s16x8 a, s16x8 b, f32x4 c) {
  return __builtin_amdgcn_mfma_f32_16x16x32_bf16(a, b, c, 0, 0, 0);
}

#define LD8(p) __hip_atomic_load((p), __ATOMIC_RELAXED, __HIP_MEMORY_SCOPE_AGENT)
#define ST8(p, v) __hip_atomic_store((p), (v), __ATOMIC_RELAXED, __HIP_MEMORY_SCOPE_AGENT)

// ---------------- setup kernels ----------------

__global__ void k_cvt_x(const float* __restrict__ x, __hip_bfloat16* __restrict__ xb, int n) {
  int i = (blockIdx.x * blockDim.x + threadIdx.x) * 4;
  if (i + 3 < n) {
    float4 v = *reinterpret_cast<const float4*>(x + i);
    xb[i + 0] = __float2bfloat16(v.x);
    xb[i + 1] = __float2bfloat16(v.y);
    xb[i + 2] = __float2bfloat16(v.z);
    xb[i + 3] = __float2bfloat16(v.w);
  }
}

// W [1024][3072] f32 -> WT [3072][1024] bf16
__global__ void k_transpose_w(const float* __restrict__ W, __hip_bfloat16* __restrict__ WT) {
  __shared__ float tile[32][33];
  int c0 = blockIdx.x * 32, r0 = blockIdx.y * 32;
  int tx = threadIdx.x & 31, ty = threadIdx.x >> 5;  // 256 threads: 32x8
#pragma unroll
  for (int i = 0; i < 32; i += 8)
    tile[ty + i][tx] = W[(size_t)(r0 + ty + i) * H3 + c0 + tx];
  __syncthreads();
#pragma unroll
  for (int i = 0; i < 32; i += 8)
    WT[(size_t)(c0 + ty + i) * HH + r0 + tx] = __float2bfloat16(tile[tx][ty + i]);
}

// ---------------- gi = x @ Wi + bi  (bf16 MFMA, 128x128 tile, BK=32) ----------------

template <bool GIF32>
__global__ __launch_bounds__(256, 2) void k_gemm_gi(
    const __hip_bfloat16* __restrict__ A,   // [16384][1024] x bf16
    const __hip_bfloat16* __restrict__ Bt,  // [3072][1024]  Wi^T bf16
    const float* __restrict__ bi,           // [3072]
    void* __restrict__ gi)                  // [16384][3072] f32 or bf16
{
  __shared__ __align__(16) __hip_bfloat16 As[128 * 32];
  __shared__ __align__(16) __hip_bfloat16 Bs[128 * 32];
  const int bid = blockIdx.x;
  const int mt = bid / 24, nt = bid % 24;
  const int m0 = mt * 128, n0 = nt * 128;
  const int tid = threadIdx.x, lane = tid & 63, w = tid >> 6;
  const int wm = w & 1, wn = w >> 1;

  f32x4 acc[4][4];
#pragma unroll
  for (int ai = 0; ai < 4; ++ai)
#pragma unroll
    for (int bj = 0; bj < 4; ++bj) acc[ai][bj] = (f32x4){0.f, 0.f, 0.f, 0.f};

  for (int k0 = 0; k0 < HH; k0 += 32) {
#pragma unroll
    for (int i = 0; i < 2; ++i) {
      const int c = w + i * 4;          // 1KB chunk id, wave-uniform
      const int idx = c * 64 + lane;    // 16B unit id
      const int row = idx >> 2, slot = idx & 3;
      __builtin_amdgcn_global_load_lds(
          (const __attribute__((address_space(1))) void*)(A + (size_t)(m0 + row) * HH + k0 + slot * 8),
          (__attribute__((address_space(3))) void*)(As + c * 512), 16, 0, 0);
      __builtin_amdgcn_global_load_lds(
          (const __attribute__((address_space(1))) void*)(Bt + (size_t)(n0 + row) * HH + k0 + slot * 8),
          (__attribute__((address_space(3))) void*)(Bs + c * 512), 16, 0, 0);
    }
    __syncthreads();
    s16x8 af[4], bf[4];
#pragma unroll
    for (int ai = 0; ai < 4; ++ai) {
      int r = wm * 64 + ai * 16 + (lane & 15);
      af[ai] = *reinterpret_cast<const s16x8*>(As + r * 32 + (lane >> 4) * 8);
    }
#pragma unroll
    for (int bj = 0; bj < 4; ++bj) {
      int r = wn * 64 + bj * 16 + (lane & 15);
      bf[bj] = *reinterpret_cast<const s16x8*>(Bs + r * 32 + (lane >> 4) * 8);
    }
#pragma unroll
    for (int ai = 0; ai < 4; ++ai)
#pragma unroll
      for (int bj = 0; bj < 4; ++bj) acc[ai][bj] = mfma16(af[ai], bf[bj], acc[ai][bj]);
    __syncthreads();
  }

#pragma unroll
  for (int ai = 0; ai < 4; ++ai) {
#pragma unroll
    for (int reg = 0; reg < 4; ++reg) {
      const size_t row = (size_t)m0 + wm * 64 + ai * 16 + (lane >> 4) * 4 + reg;
#pragma unroll
      for (int bj = 0; bj < 4; ++bj) {
        const int col = n0 + wn * 64 + bj * 16 + (lane & 15);
        float v = acc[ai][bj][reg] + bi[col];
        if (GIF32)
          reinterpret_cast<float*>(gi)[row * H3 + col] = v;
        else
          reinterpret_cast<__hip_bfloat16*>(gi)[row * H3 + col] = __float2bfloat16(v);
      }
    }
  }
}

// ---------------- persistent step kernel ----------------

// 256 WGs x 256 threads (4 waves). 4 groups (16 batches) x 64 WGs (16 j-cols).
// Wh^T slice (48 rows x 1024 k, 96 KiB) LDS-resident with XOR swizzle.
// Wave w owns K-chunk w (k in [256w,256w+256) = producers [16w,16w+16)).
// Epilogue: thread tid owns cell (b = bg0 + tid>>4, j = j0 + (tid&15)).
template <bool GIF32>
__global__ __launch_bounds__(256, 1) void k_gru(
    const void* __restrict__ gi_,
    const int* __restrict__ resets,   // [256][64]
    const float* __restrict__ h0,     // [64][1024]
    const float* __restrict__ bn,     // [1024]
    const __hip_bfloat16* __restrict__ WhT,  // [3072][1024]
    __hip_bfloat16* hseq,                    // [257][64][1024] sentinel-filled
    float* __restrict__ out)                 // [64*1024 hfinal | 256*64*1024 ys]
{
  __shared__ __align__(16) __hip_bfloat16 Bsh[48 * 1024];  // 96 KiB
  __shared__ __align__(16) f32x4 part[2][4][3][64];        // 24 KiB partials
  __shared__ __align__(8) __hip_bfloat16 hsh[16][16];      // 512 B transpose
  const int tid = threadIdx.x;
  const int wave = tid >> 6, lane = tid & 63;
  const int wg = blockIdx.x;
  const int g = (wg & 7) >> 1;                // XCD-pair -> group (perf heuristic only)
  const int s = ((wg >> 3) << 1) | (wg & 1);  // 0..63 within group
  const int bg0 = g * 16, j0 = s * 16;

  // stage Wh^T slice into LDS, XOR-swizzled: data(row, slot16B) at byte
  // row*2048 + ((slot*16) ^ ((row&7)<<4))
  for (int cch = tid; cch < 48 * 128; cch += 256) {
    const int row = cch >> 7, slot = cch & 127;
    const int gate = row >> 4, jj = row & 15;
    u32x4 v = *reinterpret_cast<const u32x4*>(WhT + (size_t)(gate * HH + j0 + jj) * HH + slot * 8);
    const int byte = row * 2048 + ((slot * 16) ^ ((row & 7) << 4));
    *reinterpret_cast<u32x4*>(reinterpret_cast<char*>(Bsh) + byte) = v;
  }

  // ---- per-thread epilogue cell: (b, j) ----
  const int bl = tid >> 4;   // 0..15, wave-aligned (bl>>2 == wave)
  const int jl = tid & 15;
  const int b = bg0 + bl, j = j0 + jl;
  const float bnj = bn[j];
  float hp = h0[(size_t)b * HH + j];
  int rstE;
  float giR, giZ, giN;
  {
    rstE = resets[b];
    if (GIF32) {
      const float* grow = reinterpret_cast<const float*>(gi_) + (size_t)b * H3;
      giR = grow[j]; giZ = grow[HH + j]; giN = grow[2 * HH + j];
    } else {
      const __hip_bfloat16* grow = reinterpret_cast<const __hip_bfloat16*>(gi_) + (size_t)b * H3;
      giR = __bfloat162float(grow[j]);
      giZ = __bfloat162float(grow[HH + j]);
      giN = __bfloat162float(grow[2 * HH + j]);
    }
  }

  // publish slot 0 (= h_{-1}): per-wave LDS transpose -> 8B agent stores
  hsh[bl][jl] = __float2bfloat16(hp);
  __syncthreads();  // also covers Bsh staging
  if (lane < 16) {
    const int prow = wave * 4 + (lane >> 2), pq = (lane & 3) * 4;
    ull pv = *reinterpret_cast<const ull*>(&hsh[prow][pq]);
    ST8(reinterpret_cast<ull*>(hseq + (size_t)g * 16384 + prow * HH + j0 + pq), pv);
  }

  // ---- consumer geometry (all 64 lanes of each wave) ----
  const int al = lane & 15;           // A-fragment batch row (group-local)
  const int koff = (lane >> 4) * 8;   // A-fragment k sub-offset (elements)
  const char* bbase = reinterpret_cast<const char*>(Bsh);
  const int xsw = (jl & 7) << 4;
  const int rb0 = jl * 2048, rb1 = (16 + jl) * 2048, rb2 = (32 + jl) * 2048;
  // canary: lane l covers producer (l&15) of this chunk at sampled row (l>>4)*4+1
  const int cprod = lane & 15, crow = (lane >> 4) * 4 + 1;

  for (int t = 0; t < TT; ++t) {
    const int rstA = resets[t * BB + bg0 + al];  // hidden under the spin
    const __hip_bfloat16* rd = hseq + (size_t)t * 65536 + g * 16384;

    // canary spin: all 16 producers of my chunk, 4 sampled rows
    {
      const ull* cp = reinterpret_cast<const ull*>(rd + crow * HH + wave * 256 + cprod * 16 + 8);
      int gq = 0;
      ull c;
      do {
        c = LD8(cp);
      } while (__any((int)(c == ~0ull)) && ++gq < (1 << 20));
    }

    // full chunk load + verify (retries rare: canary covers all producers)
    const ull* ch = reinterpret_cast<const ull*>(rd + al * HH + koff) + wave * 64;
    ull w[16];
#pragma unroll
    for (int i = 0; i < 8; ++i) {
      w[2 * i + 0] = LD8(ch + i * 8 + 0);
      w[2 * i + 1] = LD8(ch + i * 8 + 1);
    }
    {
      int gq = 0;
      for (;;) {
        unsigned bad = 0;
#pragma unroll
        for (int i = 0; i < 16; ++i) bad |= (unsigned)(w[i] == ~0ull);
        if (!__any((int)bad) || ++gq >= (1 << 18)) break;
#pragma unroll
        for (int i = 0; i < 8; ++i) {
          w[2 * i + 0] = LD8(ch + i * 8 + 0);
          w[2 * i + 1] = LD8(ch + i * 8 + 1);
        }
      }
    }

    // 24 partial MFMAs for this wave's K-range
    const ull amask = rstA ? 0ull : ~0ull;
    f32x4 aR = {0.f, 0.f, 0.f, 0.f}, aZ = {0.f, 0.f, 0.f, 0.f}, aN = {0.f, 0.f, 0.f, 0.f};
#pragma unroll
    for (int i = 0; i < 8; ++i) {
      const int kk = wave * 8 + i;
      union { ull q[2]; s16x8 v; } u;
      u.q[0] = w[2 * i + 0] & amask;
      u.q[1] = w[2 * i + 1] & amask;
      const int kb = kk * 64 + (lane >> 4) * 16;
      s16x8 b0 = *reinterpret_cast<const s16x8*>(bbase + rb0 + (kb ^ xsw));
      s16x8 b1 = *reinterpret_cast<const s16x8*>(bbase + rb1 + (kb ^ xsw));
      s16x8 b2 = *reinterpret_cast<const s16x8*>(bbase + rb2 + (kb ^ xsw));
      aR = mfma16(u.v, b0, aR);
      aZ = mfma16(u.v, b1, aZ);
      aN = mfma16(u.v, b2, aN);
    }

    const int p = t & 1;
    part[p][wave][0][lane] = aR;
    part[p][wave][1][lane] = aZ;
    part[p][wave][2][lane] = aN;
    __syncthreads();  // partials visible (parity double-buffer -> one barrier)

    // ---- distributed epilogue: each thread its (b,j) cell ----
    const int li = ((bl >> 2) << 4) | jl, el = bl & 3;
    float sR = part[p][0][0][li][el], sZ = part[p][0][1][li][el], sN = part[p][0][2][li][el];
#pragma unroll
    for (int ww = 1; ww < 4; ++ww) {
      sR += part[p][ww][0][li][el];
      sZ += part[p][ww][1][li][el];
      sN += part[p][ww][2][li][el];
    }
    const float hprev = rstE ? 0.f : hp;
    const float rg = fast_sigmoid(giR + sR);
    const float zg = fast_sigmoid(giZ + sZ);
    const float ng = fast_tanh(giN + rg * (sN + bnj));
    const float hnew = (1.0f - zg) * ng + zg * hprev;
    hp = hnew;

    // publish h_t to slot t+1: per-wave LDS transpose (wave-local rows),
    // lanes 0-15 of EACH wave store 8B -> 4-way parallel publish, no barrier
    hsh[bl][jl] = __float2bfloat16(hnew);
    if (lane < 16) {
      const int prow = wave * 4 + (lane >> 2), pq = (lane & 3) * 4;
      ull pv = *reinterpret_cast<const ull*>(&hsh[prow][pq]);
      ST8(reinterpret_cast<ull*>(hseq + (size_t)(t + 1) * 65536 + g * 16384 + prow * HH + j0 + pq),
          pv);
    }

    // ys write (off the inter-WG critical path)
    __builtin_nontemporal_store(hnew, out + 65536 + (size_t)t * 65536 + (size_t)b * HH + j);

    // prefetch next step's gi / reset (consumed after next canary)
    const int tn = (t + 1 < TT) ? t + 1 : t;
    rstE = resets[tn * BB + b];
    if (GIF32) {
      const float* grow = reinterpret_cast<const float*>(gi_) + (size_t)(tn * BB + b) * H3;
      giR = grow[j]; giZ = grow[HH + j]; giN = grow[2 * HH + j];
    } else {
      const __hip_bfloat16* grow =
          reinterpret_cast<const __hip_bfloat16*>(gi_) + (size_t)(tn * BB + b) * H3;
      giR = __bfloat162float(grow[j]);
      giZ = __bfloat162float(grow[HH + j]);
      giN = __bfloat162float(grow[2 * HH + j]);
    }
  }

  out[(size_t)b * HH + j] = hp;
}

// ---------------- launch ----------------

extern "C" void kernel_launch(void* const* d_in, const int* in_sizes, int n_in,
                              void* d_out, int out_size, void* d_ws, size_t ws_size,
                              hipStream_t stream) {
  const float* x      = (const float*)d_in[0];  // [256,64,1024]
  const int* resets   = (const int*)d_in[1];    // [256,64]
  const float* h0     = (const float*)d_in[2];  // [64,1024]
  const float* Wi     = (const float*)d_in[3];  // [1024,3072]
  const float* bi     = (const float*)d_in[4];  // [3072]
  const float* Wh     = (const float*)d_in[5];  // [1024,3072]
  const float* bn     = (const float*)d_in[6];  // [1024]
  (void)in_sizes; (void)n_in; (void)out_size;

  char* ws = (char*)d_ws;
  // region0: xb [16384][1024] bf16 (33,554,432 B), dead after gemm, then
  //          reused as hseq [257][64][1024] bf16 (33,685,504 B)
  __hip_bfloat16* xb   = (__hip_bfloat16*)(ws);
  __hip_bfloat16* hseq = (__hip_bfloat16*)(ws);
  __hip_bfloat16* WiT  = (__hip_bfloat16*)(ws + 33685504);  // 6,291,456 B
  __hip_bfloat16* WhT  = (__hip_bfloat16*)(ws + 39976960);  // 6,291,456 B
  void* gi             = (void*)(ws + 46268416);

  const bool gif32 = ws_size >= 46268416ull + (size_t)16384 * 3072 * 4;

  k_cvt_x<<<16384, 256, 0, stream>>>(x, xb, TT * BB * HH);
  k_transpose_w<<<dim3(96, 32), 256, 0, stream>>>(Wi, WiT);
  k_transpose_w<<<dim3(96, 32), 256, 0, stream>>>(Wh, WhT);
  if (gif32) {
    k_gemm_gi<true><<<3072, 256, 0, stream>>>(xb, WiT, bi, gi);
    // xb dead; sentinel-fill hseq (0xFF = -NaN bf16 words)
    hipMemsetAsync(hseq, 0xFF, 33685504, stream);
    k_gru<true><<<256, 256, 0, stream>>>(gi, resets, h0, bn, WhT, hseq, (float*)d_out);
  } else {
    k_gemm_gi<false><<<3072, 256, 0, stream>>>(xb, WiT, bi, gi);
    hipMemsetAsync(hseq, 0xFF, 33685504, stream);
    k_gru<false><<<256, 256, 0, stream>>>(gi, resets, h0, bn, WhT, hseq, (float*)d_out);
  }
}